// Round 1
// baseline (581.080 us; speedup 1.0000x reference)
//
#include <hip/hip_runtime.h>

#define V 255
#define L 16
#define E (V*L)      // 4080
#define P 8
#define CLIPV 10.0f

__device__ __forceinline__ float fast_tanh(float x) {
    // |x| <= 5 here (input pre-clipped to [-10,10], then *0.5)
    float e = __expf(2.0f * x);
    return __fdividef(e - 1.0f, e + 1.0f);
}

// MODE 0: write eo to workspace buffer
// MODE 1: atomicAdd into out via inverse permutation
template <int MODE>
__global__ __launch_bounds__(256) void bp_kernel(
    const float* __restrict__ x,
    const float* __restrict__ msg,
    const float* __restrict__ oddw_v,
    const float* __restrict__ oddw_e,
    const float* __restrict__ w_e_out,
    const int*   __restrict__ perma,
    const int*   __restrict__ rc_idx,
    const int*   __restrict__ cr_idx,
    float* __restrict__ eo_ws,     // MODE 0
    const int* __restrict__ invp,  // MODE 1
    float* __restrict__ out)       // MODE 1
{
    __shared__ float ev[E];
    __shared__ float oo[E];
    __shared__ float xg[V + 1];
    __shared__ float wm[L * L];
    __shared__ float wvs[L];

    const int tid = threadIdx.x;
    const int blk = blockIdx.x;
    const int b = blk >> 3;
    const int p = blk & 7;

    // stage message -> ev (coalesced)
    const float* mrow = msg + (size_t)blk * E;
    for (int i = tid; i < E; i += 256) ev[i] = mrow[i];

    // gathered x values: xg[v] = x[b, perma[p, v+1]]
    const float* xrow = x + b * (V + 1);
    const int* prow = perma + p * (V + 1);
    if (tid < V) xg[tid] = xrow[prow[tid + 1]];

    const int v = tid;           // check-node index, active if v < V
    int rci[L], cri[L];
    if (v < V) {
#pragma unroll
        for (int l = 0; l < L; ++l) {
            rci[l] = rc_idx[v * L + l];
            cri[l] = cr_idx[v * L + l];
        }
    }

    for (int t = 0; t < 5; ++t) {
        // stage weights for round t; diag of we masked to 0
        {
            int l = tid >> 4, m = tid & 15;
            float w = oddw_e[t * L * L + tid];
            wm[tid] = (l == m) ? 0.0f : w;
            if (tid < L) wvs[tid] = oddw_v[t * L + tid];
        }
        __syncthreads();   // weights + ev ready

        if (v < V) {
            // odd layer: gather via rc, 16x16 matvec, tanh
            float eg[L];
#pragma unroll
            for (int l = 0; l < L; ++l) eg[l] = ev[rci[l]];
            float s[L];
            const float xv = xg[v];
#pragma unroll
            for (int m = 0; m < L; ++m) s[m] = xv * wvs[m];
#pragma unroll
            for (int l = 0; l < L; ++l) {
                const float el = eg[l];
#pragma unroll
                for (int m = 0; m < L; ++m) s[m] += el * wm[l * L + m];
            }
#pragma unroll
            for (int m = 0; m < L; ++m) {
                float tt = fminf(fmaxf(s[m], -CLIPV), CLIPV);
                oo[v * L + m] = fast_tanh(0.5f * tt);
            }
        }
        __syncthreads();   // oo complete, ev fully consumed

        if (v < V) {
            // even layer: gather via cr, leave-one-out product, log-ratio
            float e2[L];
#pragma unroll
            for (int l = 0; l < L; ++l) {
                float q = oo[cri[l]];
                e2[l] = (q == 0.0f) ? 1.0f : q;
            }
            float pre[L + 1];
            pre[0] = 1.0f;
#pragma unroll
            for (int l = 0; l < L; ++l) pre[l + 1] = pre[l] * e2[l];
            float suf = 1.0f;
#pragma unroll
            for (int l = L - 1; l >= 0; --l) {
                float r = pre[l] * suf;
                suf *= e2[l];
                if (t == 0) r = fminf(fmaxf(r, -CLIPV), CLIPV);
                float arg = __fdividef(1.0f + r, 1.0f - r + 1e-9f) + 1e-9f;
                ev[v * L + l] = __logf(arg);
            }
        }
        __syncthreads();   // ev complete, oo fully consumed
    }

    // final: gather via rc, dot with w_e_out
    if (v < V) {
        float s = 0.0f;
#pragma unroll
        for (int l = 0; l < L; ++l) s += ev[rci[l]] * w_e_out[l];
        if (MODE == 0) {
            eo_ws[(size_t)blk * V + v] = s;
        } else {
            int jpos = invp[p * (V + 1) + (v + 1)];
            atomicAdd(&out[b * (V + 1) + jpos], s);
        }
    }
}

// gather-sum epilogue (MODE 0 path)
__global__ __launch_bounds__(256) void out_kernel(
    const float* __restrict__ x,
    const float* __restrict__ eo_ws,
    const int* __restrict__ perma,
    float* __restrict__ out)
{
    const int b = blockIdx.x;
    const int j = threadIdx.x;   // 0..255
    float acc = x[b * (V + 1) + j];
#pragma unroll
    for (int p = 0; p < P; ++p) {
        int idx = perma[p * (V + 1) + j];
        if (idx > 0) acc += eo_ws[((size_t)(b * P + p)) * V + (idx - 1)];
    }
    out[b * (V + 1) + j] = acc;
}

// fallback helpers (MODE 1 path)
__global__ __launch_bounds__(256) void inv_kernel(const int* __restrict__ perma,
                                                  int* __restrict__ invp)
{
    int p = blockIdx.x, j = threadIdx.x;
    invp[p * (V + 1) + perma[p * (V + 1) + j]] = j;
}

__global__ __launch_bounds__(256) void copy_kernel(const float* __restrict__ x,
                                                   float* __restrict__ out, int n)
{
    int i = blockIdx.x * 256 + threadIdx.x;
    if (i < n) out[i] = x[i];
}

extern "C" void kernel_launch(void* const* d_in, const int* in_sizes, int n_in,
                              void* d_out, int out_size, void* d_ws, size_t ws_size,
                              hipStream_t stream)
{
    const float* x       = (const float*)d_in[0];
    const float* msg     = (const float*)d_in[1];
    const float* oddw_v  = (const float*)d_in[2];
    const float* oddw_e  = (const float*)d_in[3];
    const float* w_e_out = (const float*)d_in[4];
    const int*   perma   = (const int*)d_in[5];
    const int*   rc      = (const int*)d_in[6];
    const int*   cr      = (const int*)d_in[7];
    float* out = (float*)d_out;

    const int Bx = in_sizes[0] / (V + 1);
    const size_t need = (size_t)Bx * P * V * sizeof(float);

    if (ws_size >= need) {
        float* eo = (float*)d_ws;
        hipLaunchKernelGGL((bp_kernel<0>), dim3(Bx * P), dim3(256), 0, stream,
                           x, msg, oddw_v, oddw_e, w_e_out, perma, rc, cr,
                           eo, (const int*)nullptr, (float*)nullptr);
        hipLaunchKernelGGL(out_kernel, dim3(Bx), dim3(256), 0, stream,
                           x, eo, perma, out);
    } else {
        // atomic fallback: needs P*(V+1)*4 = 8KB workspace for inverse perm
        int* invp = (int*)d_ws;
        hipLaunchKernelGGL(inv_kernel, dim3(P), dim3(V + 1), 0, stream, perma, invp);
        hipLaunchKernelGGL(copy_kernel, dim3((out_size + 255) / 256), dim3(256), 0, stream,
                           x, out, out_size);
        hipLaunchKernelGGL((bp_kernel<1>), dim3(Bx * P), dim3(256), 0, stream,
                           x, msg, oddw_v, oddw_e, w_e_out, perma, rc, cr,
                           (float*)nullptr, invp, out);
    }
}

// Round 2
// 272.966 us; speedup vs baseline: 2.1288x; 2.1288x over previous
//
#include <hip/hip_runtime.h>

#define V 255
#define L 16
#define E (V*L)      // 4080
#define P 8
#define CLIPV 10.0f

__device__ __forceinline__ float fast_tanh(float x) {
    // |x| <= 5 here (input pre-clipped to [-10,10], then *0.5)
    float e = __expf(2.0f * x);
    return __fdividef(e - 1.0f, e + 1.0f);
}

// Transposed LDS layout: element (v,l) of the [V][L] state lives at l*V + v.
__device__ __forceinline__ int tr_idx(int i) {
    return (i & (L - 1)) * V + (i >> 4);
}

template <int MODE>
__global__ __launch_bounds__(256) void bp_kernel(
    const float* __restrict__ x,
    const float* __restrict__ msg,
    const float* __restrict__ oddw_v,
    const float* __restrict__ oddw_e,
    const float* __restrict__ w_e_out,
    const int*   __restrict__ perma,
    const int*   __restrict__ rc_idx,
    const int*   __restrict__ cr_idx,
    float* __restrict__ eo_ws,     // MODE 0
    const int* __restrict__ invp,  // MODE 1
    float* __restrict__ out)       // MODE 1
{
    __shared__ float evT[E];   // [L][V]
    __shared__ float ooT[E];   // [L][V]
    __shared__ float xg[V + 1];
    __shared__ float wm[L * L];
    __shared__ float wvs[L];
    __shared__ float weo[L];

    const int tid = threadIdx.x;
    const int blk = blockIdx.x;
    const int b = blk >> 3;
    const int p = blk & 7;
    const int v = tid;           // check-node index, active if v < V

    // stage message -> evT. Thread v loads row v (16 consecutive floats, as
    // 4x float4 => coalesced 64B/lane), writes transposed (conflict-free).
    if (v < V) {
        const float4* mrow4 = (const float4*)(msg + (size_t)blk * E + v * L);
#pragma unroll
        for (int q = 0; q < 4; ++q) {
            float4 m4 = mrow4[q];
            evT[(4 * q + 0) * V + v] = m4.x;
            evT[(4 * q + 1) * V + v] = m4.y;
            evT[(4 * q + 2) * V + v] = m4.z;
            evT[(4 * q + 3) * V + v] = m4.w;
        }
    }

    // gathered x values: xg[v] = x[b, perma[p, v+1]]
    const float* xrow = x + b * (V + 1);
    const int* prow = perma + p * (V + 1);
    if (tid < V) xg[tid] = xrow[prow[tid + 1]];
    if (tid < L) weo[tid] = w_e_out[tid];

    int rci[L], cri[L];   // transposed LDS addresses
    if (v < V) {
#pragma unroll
        for (int l = 0; l < L; ++l) {
            rci[l] = tr_idx(rc_idx[v * L + l]);
            cri[l] = tr_idx(cr_idx[v * L + l]);
        }
    }

    for (int t = 0; t < 5; ++t) {
        // stage weights for round t; diag of we masked to 0
        {
            int l = tid >> 4, m = tid & 15;
            float w = oddw_e[t * L * L + tid];
            wm[tid] = (l == m) ? 0.0f : w;
            if (tid < L) wvs[tid] = oddw_v[t * L + tid];
        }
        __syncthreads();   // weights + evT ready

        if (v < V) {
            // odd layer: gather via rc (conflict-free), 16x16 matvec, tanh
            float eg[L];
#pragma unroll
            for (int l = 0; l < L; ++l) eg[l] = evT[rci[l]];
            float s[L];
            const float xv = xg[v];
#pragma unroll
            for (int m = 0; m < L; ++m) s[m] = xv * wvs[m];
#pragma unroll
            for (int l = 0; l < L; ++l) {
                const float el = eg[l];
#pragma unroll
                for (int m = 0; m < L; ++m) s[m] += el * wm[l * L + m];
            }
#pragma unroll
            for (int m = 0; m < L; ++m) {
                float tt = fminf(fmaxf(s[m], -CLIPV), CLIPV);
                ooT[m * V + v] = fast_tanh(0.5f * tt);   // conflict-free
            }
        }
        __syncthreads();   // ooT complete, evT fully consumed

        if (v < V) {
            // even layer: gather via cr (conflict-free), leave-one-out
            // product via prefix/suffix, log-ratio
            float e2[L];
#pragma unroll
            for (int l = 0; l < L; ++l) {
                float q = ooT[cri[l]];
                e2[l] = (q == 0.0f) ? 1.0f : q;
            }
            float pre[L + 1];
            pre[0] = 1.0f;
#pragma unroll
            for (int l = 0; l < L; ++l) pre[l + 1] = pre[l] * e2[l];
            float suf = 1.0f;
#pragma unroll
            for (int l = L - 1; l >= 0; --l) {
                float r = pre[l] * suf;
                suf *= e2[l];
                if (t == 0) r = fminf(fmaxf(r, -CLIPV), CLIPV);
                float arg = __fdividef(1.0f + r, 1.0f - r + 1e-9f) + 1e-9f;
                evT[l * V + v] = __logf(arg);            // conflict-free
            }
        }
        __syncthreads();   // evT complete, ooT fully consumed
    }

    // final: gather via rc, dot with w_e_out
    if (v < V) {
        float s = 0.0f;
#pragma unroll
        for (int l = 0; l < L; ++l) s += evT[rci[l]] * weo[l];
        if (MODE == 0) {
            eo_ws[(size_t)blk * V + v] = s;
        } else {
            int jpos = invp[p * (V + 1) + (v + 1)];
            atomicAdd(&out[b * (V + 1) + jpos], s);
        }
    }
}

// gather-sum epilogue (MODE 0 path)
__global__ __launch_bounds__(256) void out_kernel(
    const float* __restrict__ x,
    const float* __restrict__ eo_ws,
    const int* __restrict__ perma,
    float* __restrict__ out)
{
    const int b = blockIdx.x;
    const int j = threadIdx.x;   // 0..255
    float acc = x[b * (V + 1) + j];
#pragma unroll
    for (int p = 0; p < P; ++p) {
        int idx = perma[p * (V + 1) + j];
        if (idx > 0) acc += eo_ws[((size_t)(b * P + p)) * V + (idx - 1)];
    }
    out[b * (V + 1) + j] = acc;
}

// fallback helpers (MODE 1 path)
__global__ __launch_bounds__(256) void inv_kernel(const int* __restrict__ perma,
                                                  int* __restrict__ invp)
{
    int p = blockIdx.x, j = threadIdx.x;
    invp[p * (V + 1) + perma[p * (V + 1) + j]] = j;
}

__global__ __launch_bounds__(256) void copy_kernel(const float* __restrict__ x,
                                                   float* __restrict__ out, int n)
{
    int i = blockIdx.x * 256 + threadIdx.x;
    if (i < n) out[i] = x[i];
}

extern "C" void kernel_launch(void* const* d_in, const int* in_sizes, int n_in,
                              void* d_out, int out_size, void* d_ws, size_t ws_size,
                              hipStream_t stream)
{
    const float* x       = (const float*)d_in[0];
    const float* msg     = (const float*)d_in[1];
    const float* oddw_v  = (const float*)d_in[2];
    const float* oddw_e  = (const float*)d_in[3];
    const float* w_e_out = (const float*)d_in[4];
    const int*   perma   = (const int*)d_in[5];
    const int*   rc      = (const int*)d_in[6];
    const int*   cr      = (const int*)d_in[7];
    float* out = (float*)d_out;

    const int Bx = in_sizes[0] / (V + 1);
    const size_t need = (size_t)Bx * P * V * sizeof(float);

    if (ws_size >= need) {
        float* eo = (float*)d_ws;
        hipLaunchKernelGGL((bp_kernel<0>), dim3(Bx * P), dim3(256), 0, stream,
                           x, msg, oddw_v, oddw_e, w_e_out, perma, rc, cr,
                           eo, (const int*)nullptr, (float*)nullptr);
        hipLaunchKernelGGL(out_kernel, dim3(Bx), dim3(256), 0, stream,
                           x, eo, perma, out);
    } else {
        // atomic fallback: needs P*(V+1)*4 = 8KB workspace for inverse perm
        int* invp = (int*)d_ws;
        hipLaunchKernelGGL(inv_kernel, dim3(P), dim3(V + 1), 0, stream, perma, invp);
        hipLaunchKernelGGL(copy_kernel, dim3((out_size + 255) / 256), dim3(256), 0, stream,
                           x, out, out_size);
        hipLaunchKernelGGL((bp_kernel<1>), dim3(Bx * P), dim3(256), 0, stream,
                           x, msg, oddw_v, oddw_e, w_e_out, perma, rc, cr,
                           (float*)nullptr, invp, out);
    }
}

// Round 3
// 270.531 us; speedup vs baseline: 2.1479x; 1.0090x over previous
//
#include <hip/hip_runtime.h>

#define V 255
#define L 16
#define E (V*L)      // 4080
#define P 8
#define CLIPV 10.0f

__device__ __forceinline__ float fast_tanh_half(float t) {
    // tanh(0.5*t), |t| <= 10
    float e = __expf(t);
    return __fdividef(e - 1.0f, e + 1.0f);
}

// Transposed (col-major) layout: element (v,l) of the [V][L] state -> l*V + v.
__device__ __forceinline__ int tr_idx(int i) {
    return (i & (L - 1)) * V + (i >> 4);
}

template <int MODE>
__global__ __launch_bounds__(256) void bp_kernel(
    const float* __restrict__ x,
    const float* __restrict__ msg,
    const float* __restrict__ oddw_v,
    const float* __restrict__ oddw_e,
    const float* __restrict__ w_e_out,
    const int*   __restrict__ perma,
    const int*   __restrict__ rc_idx,
    const int*   __restrict__ cr_idx,
    float* __restrict__ eo_ws,     // MODE 0
    const int* __restrict__ invp,  // MODE 1
    float* __restrict__ out)       // MODE 1
{
    __shared__ float S[E];             // single state buffer, [L][V]
    __shared__ float wm5[5 * L * L];   // all 5 rounds' edge weights, diag-masked
    __shared__ float wvs5[5 * L];
    __shared__ float weo[L];

    const int tid = threadIdx.x;
    const int blk = blockIdx.x;
    const int b = blk >> 3;
    const int p = blk & 7;
    const int v = tid;                 // check-node index, active if v < V

    // stage message -> S (transposed, conflict-free writes)
    if (v < V) {
        const float4* mrow4 = (const float4*)(msg + (size_t)blk * E + v * L);
#pragma unroll
        for (int q = 0; q < 4; ++q) {
            float4 m4 = mrow4[q];
            S[(4 * q + 0) * V + v] = m4.x;
            S[(4 * q + 1) * V + v] = m4.y;
            S[(4 * q + 2) * V + v] = m4.z;
            S[(4 * q + 3) * V + v] = m4.w;
        }
    }

    // stage all 5 rounds' weights once (diag of we masked to 0)
    {
        const int l = tid >> 4, m = tid & 15;
#pragma unroll
        for (int t = 0; t < 5; ++t) {
            float w = oddw_e[t * L * L + tid];
            wm5[t * L * L + tid] = (l == m) ? 0.0f : w;
        }
        if (tid < 5 * L) wvs5[tid] = oddw_v[tid];
        if (tid < L) weo[tid] = w_e_out[tid];
    }

    // per-thread x value (register, no LDS)
    float xv = 0.0f;
    if (v < V) xv = x[b * (V + 1) + perma[p * (V + 1) + v + 1]];

    int rci[L], cri[L];   // transposed LDS addresses
    if (v < V) {
#pragma unroll
        for (int l = 0; l < L; ++l) {
            rci[l] = tr_idx(rc_idx[v * L + l]);
            cri[l] = tr_idx(cr_idx[v * L + l]);
        }
    }

    __syncthreads();   // S + weights ready

    for (int t = 0; t < 5; ++t) {
        const float* wm = &wm5[t * L * L];

        // ---- odd layer ----
        float eg[L];
        if (v < V) {
#pragma unroll
            for (int l = 0; l < L; ++l) eg[l] = S[rci[l]];   // conflict-free
        }
        __syncthreads();   // all gathers done; S may now be overwritten

        if (v < V) {
            float s[L];
            const float wv0 = xv;
#pragma unroll
            for (int m = 0; m < L; ++m) s[m] = wv0 * wvs5[t * L + m];
#pragma unroll
            for (int l = 0; l < L; ++l) {
                const float el = eg[l];
#pragma unroll
                for (int m = 0; m < L; ++m) s[m] += el * wm[l * L + m];
            }
#pragma unroll
            for (int m = 0; m < L; ++m) {
                float tt = fminf(fmaxf(s[m], -CLIPV), CLIPV);
                S[m * V + v] = fast_tanh_half(tt);           // conflict-free
            }
        }
        __syncthreads();   // odd outputs complete

        // ---- even layer ----
        float e2[L];
        if (v < V) {
#pragma unroll
            for (int l = 0; l < L; ++l) {
                float q = S[cri[l]];                          // conflict-free
                e2[l] = (q == 0.0f) ? 1.0f : q;
            }
        }
        __syncthreads();   // all gathers done; S may now be overwritten

        if (v < V) {
            float pre[L + 1];
            pre[0] = 1.0f;
#pragma unroll
            for (int l = 0; l < L; ++l) pre[l + 1] = pre[l] * e2[l];
            float suf = 1.0f;
#pragma unroll
            for (int l = L - 1; l >= 0; --l) {
                float r = pre[l] * suf;
                suf *= e2[l];
                if (t == 0) r = fminf(fmaxf(r, -CLIPV), CLIPV);
                float arg = __fdividef(1.0f + r, 1.0f - r + 1e-9f) + 1e-9f;
                S[l * V + v] = __logf(arg);                   // conflict-free
            }
        }
        __syncthreads();   // even outputs complete
    }

    // final: gather via rc, dot with w_e_out
    if (v < V) {
        float s = 0.0f;
#pragma unroll
        for (int l = 0; l < L; ++l) s += S[rci[l]] * weo[l];
        if (MODE == 0) {
            eo_ws[(size_t)blk * V + v] = s;
        } else {
            int jpos = invp[p * (V + 1) + (v + 1)];
            atomicAdd(&out[b * (V + 1) + jpos], s);
        }
    }
}

// gather-sum epilogue (MODE 0 path)
__global__ __launch_bounds__(256) void out_kernel(
    const float* __restrict__ x,
    const float* __restrict__ eo_ws,
    const int* __restrict__ perma,
    float* __restrict__ out)
{
    const int b = blockIdx.x;
    const int j = threadIdx.x;   // 0..255
    float acc = x[b * (V + 1) + j];
#pragma unroll
    for (int p = 0; p < P; ++p) {
        int idx = perma[p * (V + 1) + j];
        if (idx > 0) acc += eo_ws[((size_t)(b * P + p)) * V + (idx - 1)];
    }
    out[b * (V + 1) + j] = acc;
}

// fallback helpers (MODE 1 path)
__global__ __launch_bounds__(256) void inv_kernel(const int* __restrict__ perma,
                                                  int* __restrict__ invp)
{
    int p = blockIdx.x, j = threadIdx.x;
    invp[p * (V + 1) + perma[p * (V + 1) + j]] = j;
}

__global__ __launch_bounds__(256) void copy_kernel(const float* __restrict__ x,
                                                   float* __restrict__ out, int n)
{
    int i = blockIdx.x * 256 + threadIdx.x;
    if (i < n) out[i] = x[i];
}

extern "C" void kernel_launch(void* const* d_in, const int* in_sizes, int n_in,
                              void* d_out, int out_size, void* d_ws, size_t ws_size,
                              hipStream_t stream)
{
    const float* x       = (const float*)d_in[0];
    const float* msg     = (const float*)d_in[1];
    const float* oddw_v  = (const float*)d_in[2];
    const float* oddw_e  = (const float*)d_in[3];
    const float* w_e_out = (const float*)d_in[4];
    const int*   perma   = (const int*)d_in[5];
    const int*   rc      = (const int*)d_in[6];
    const int*   cr      = (const int*)d_in[7];
    float* out = (float*)d_out;

    const int Bx = in_sizes[0] / (V + 1);
    const size_t need = (size_t)Bx * P * V * sizeof(float);

    if (ws_size >= need) {
        float* eo = (float*)d_ws;
        hipLaunchKernelGGL((bp_kernel<0>), dim3(Bx * P), dim3(256), 0, stream,
                           x, msg, oddw_v, oddw_e, w_e_out, perma, rc, cr,
                           eo, (const int*)nullptr, (float*)nullptr);
        hipLaunchKernelGGL(out_kernel, dim3(Bx), dim3(256), 0, stream,
                           x, eo, perma, out);
    } else {
        // atomic fallback: needs P*(V+1)*4 = 8KB workspace for inverse perm
        int* invp = (int*)d_ws;
        hipLaunchKernelGGL(inv_kernel, dim3(P), dim3(V + 1), 0, stream, perma, invp);
        hipLaunchKernelGGL(copy_kernel, dim3((out_size + 255) / 256), dim3(256), 0, stream,
                           x, out, out_size);
        hipLaunchKernelGGL((bp_kernel<1>), dim3(Bx * P), dim3(256), 0, stream,
                           x, msg, oddw_v, oddw_e, w_e_out, perma, rc, cr,
                           (float*)nullptr, invp, out);
    }
}